// Round 13
// baseline (436.677 us; speedup 1.0000x reference)
//
#include <hip/hip_runtime.h>

#define DD 48
#define TT 512
#define BB 512
#define STRIDE 64  // bp row stride (cols 0..63, lanes 48..63 are dump)
#define PF 8       // emit ring depth == inner unroll

// slot k holds alpha[lane ^ PERM(k)]; stage order: xor1, xor2, xor32, xor4, xor8, xor16
__host__ __device__ constexpr int PERMK(int k) {
  return ((k & 1) ? 1 : 0) | ((k & 2) ? 2 : 0) | ((k & 4) ? 32 : 0) |
         ((k & 8) ? 4 : 0) | ((k & 16) ? 8 : 0) | ((k & 32) ? 16 : 0);
}

template <int CTRL>
__device__ __forceinline__ float dpp_f(float v) {
  return __int_as_float(__builtin_amdgcn_mov_dpp(__float_as_int(v), CTRL, 0xF, 0xF, true));
}
template <int PAT>
__device__ __forceinline__ float swz_f(float v) {
  return __int_as_float(__builtin_amdgcn_ds_swizzle(__float_as_int(v), PAT));
}
__device__ __forceinline__ float bperm_f(int addr, float v) {
  return __int_as_float(__builtin_amdgcn_ds_bpermute(addr, __float_as_int(v)));
}
__device__ __forceinline__ float max3f(float a, float b, float c) {
  return fmaxf(fmaxf(a, b), c);
}
__device__ __forceinline__ unsigned min3u(unsigned a, unsigned b, unsigned c) {
  unsigned m = a < b ? a : b; return m < c ? m : c;
}

// butterfly share: a[0]=alpha -> a[k]=alpha[lane^PERMK(k)]
#define SHARE(A, ALPHA, BPADDR)                                          \
  {                                                                      \
    A[0] = (ALPHA);                                                      \
    A[1] = dpp_f<0xB1>(A[0]); /* quad_perm [1,0,3,2] = xor1 */           \
    A[2] = dpp_f<0x4E>(A[0]); /* quad_perm [2,3,0,1] = xor2 */           \
    A[3] = dpp_f<0x4E>(A[1]);                                            \
    _Pragma("unroll")                                                    \
    for (int m = 0; m < 4; ++m) A[4 + m] = bperm_f((BPADDR), A[m]);      \
    _Pragma("unroll")                                                    \
    for (int m = 0; m < 8; ++m) A[8 + m] = swz_f<0x101F>(A[m]);  /* xor4 */  \
    _Pragma("unroll")                                                    \
    for (int m = 0; m < 16; ++m) A[16 + m] = swz_f<0x201F>(A[m]); /* xor8 */ \
    _Pragma("unroll")                                                    \
    for (int m = 0; m < 32; ++m) A[32 + m] = swz_f<0x401F>(A[m]); /* xor16 */\
  }

// 64-wide value max via max3 tree (VCC-free)
__device__ __forceinline__ float vmax64(const float* s) {
  float m1[22];
#pragma unroll
  for (int k = 0; k < 21; ++k) m1[k] = max3f(s[3 * k], s[3 * k + 1], s[3 * k + 2]);
  m1[21] = s[63];
  float m2[8];
#pragma unroll
  for (int k = 0; k < 7; ++k) m2[k] = max3f(m1[3 * k], m1[3 * k + 1], m1[3 * k + 2]);
  m2[7] = m1[21];
  float m3a = max3f(m2[0], m2[1], m2[2]);
  float m3b = max3f(m2[3], m2[4], m2[5]);
  float m3c = fmaxf(m2[6], m2[7]);
  return max3f(m3a, m3b, m3c);
}

// smallest origin index among slots with s[k]==best (exact first-index argmax)
__device__ __forceinline__ unsigned argmin_match64(const float* s, float best,
                                                   const unsigned* io) {
  unsigned u[64];
#pragma unroll
  for (int k = 0; k < 64; ++k) u[k] = (s[k] == best) ? io[k] : 64u;
  unsigned n1[22];
#pragma unroll
  for (int k = 0; k < 21; ++k) n1[k] = min3u(u[3 * k], u[3 * k + 1], u[3 * k + 2]);
  n1[21] = u[63];
  unsigned n2[8];
#pragma unroll
  for (int k = 0; k < 7; ++k) n2[k] = min3u(n1[3 * k], n1[3 * k + 1], n1[3 * k + 2]);
  n2[7] = n1[21];
  unsigned na = min3u(n2[0], n2[1], n2[2]);
  unsigned nb = min3u(n2[3], n2[4], n2[5]);
  unsigned nc = n2[6] < n2[7] ? n2[6] : n2[7];
  return min3u(na, nb, nc);
}

__global__ __launch_bounds__(64, 1) void crf_viterbi(const float* __restrict__ logits,
                                                     const int* __restrict__ lens,
                                                     const float* __restrict__ trans,
                                                     int* __restrict__ out) {
  const int b = blockIdx.x;
  const int j = threadIdx.x;          // lane = output tag column (0..47 live)
  const int jj = j < DD ? j : DD - 1; // clamp for safe emit reads

  __shared__ unsigned char bp[TT * STRIDE]; // 32 KB backpointers

  const int bpaddr = ((j ^ 32) & 63) * 4; // bpermute addr for xor32 stage

  // tcol[k] = trans[origin(k)][j] in the butterfly slot arrangement; invalid -> -1e30
  float tcol[64];
  unsigned io[64];
#pragma unroll
  for (int k = 0; k < 64; ++k) {
    int o = j ^ PERMK(k);
    io[k] = (unsigned)o;
    bool valid = (j < DD) && (o < DD);
    tcol[k] = valid ? trans[o * DD + j] : -1e30f;
  }

  const float* lg = logits + (size_t)b * TT * DD;
  const int L = lens[b];

  float alpha = lg[jj]; // lane j owns alpha[j] (lanes >=48: junk, masked everywhere)

  // 8-deep emit ring, static slots
  float e0 = lg[1 * DD + jj], e1 = lg[2 * DD + jj],
        e2 = lg[3 * DD + jj], e3 = lg[4 * DD + jj],
        e4 = lg[5 * DD + jj], e5 = lg[6 * DD + jj],
        e6 = lg[7 * DD + jj], e7 = lg[8 * DD + jj];

#define STEP(EV)                                        \
  {                                                     \
    float a[64];                                        \
    SHARE(a, alpha, bpaddr);                            \
    float s[64];                                        \
    _Pragma("unroll")                                   \
    for (int k = 0; k < 64; ++k) s[k] = a[k] + tcol[k]; \
    float best = vmax64(s);                             \
    alpha = best + (EV);                                \
    unsigned idx = argmin_match64(s, best, io);         \
    bp[t * STRIDE + j] = (unsigned char)idx;            \
  }

#define RELOAD(ES)                                 \
  {                                                \
    int r = t + PF; r = r > TT - 1 ? TT - 1 : r;   \
    ES = lg[r * DD + jj];                          \
  }

  int t = 1;
  while (t < L) {
    STEP(e0); RELOAD(e0); ++t; if (t >= L) break;
    STEP(e1); RELOAD(e1); ++t; if (t >= L) break;
    STEP(e2); RELOAD(e2); ++t; if (t >= L) break;
    STEP(e3); RELOAD(e3); ++t; if (t >= L) break;
    STEP(e4); RELOAD(e4); ++t; if (t >= L) break;
    STEP(e5); RELOAD(e5); ++t; if (t >= L) break;
    STEP(e6); RELOAD(e6); ++t; if (t >= L) break;
    STEP(e7); RELOAD(e7); ++t;
  }
#undef STEP
#undef RELOAD

  __syncthreads(); // single wave; ordering formality before backtrack

  // last_tag = argmax_j alpha[j]: share then reduce (dead lanes hold ~-1e30,
  // auto-excluded; result uniform across lanes)
  int btag;
  {
    float a[64];
    SHARE(a, alpha, bpaddr);
    float best = vmax64(a);
    btag = (int)argmin_match64(a, best, io);
  }

  int* ob = out + (size_t)b * TT;
  if (j == 0) ob[L - 1] = btag;

  // Backtrack by function composition: H[j] = tag at time t given final tag j.
  int H = j;
  for (int tt = L - 1; tt >= 1; --tt) {
    int v = bp[tt * STRIDE + jj]; // addr independent of H -> pipelined
    H = __shfl(v, H, 64);         // H' = bp_t[H]
    if (j == btag) ob[tt - 1] = H;
  }

  // zero the padded tail t >= L
  for (int tt = L + j; tt < TT; tt += 64) ob[tt] = 0;
}

extern "C" void kernel_launch(void* const* d_in, const int* in_sizes, int n_in,
                              void* d_out, int out_size, void* d_ws, size_t ws_size,
                              hipStream_t stream) {
  const float* logits = (const float*)d_in[0];
  const int* lens     = (const int*)d_in[1];
  const float* trans  = (const float*)d_in[2];
  int* out            = (int*)d_out;
  (void)in_sizes; (void)n_in; (void)out_size; (void)d_ws; (void)ws_size;
  crf_viterbi<<<BB, 64, 0, stream>>>(logits, lens, trans, out);
}

// Round 14
// 284.719 us; speedup vs baseline: 1.5337x; 1.5337x over previous
//
#include <hip/hip_runtime.h>

#define DD 48
#define TT 512
#define BB 512
#define STRIDE 64   // bp row stride
#define ROWS (TT + 8)

__device__ __forceinline__ float readlane_f(float v, int lane) {
  return __int_as_float(__builtin_amdgcn_readlane(__float_as_int(v), lane));
}

// branchless freeze: return (t < L) ? cand : old   (no VCC, no branch)
__device__ __forceinline__ float freeze(float old_, float cand, int t, int L) {
  unsigned m = (unsigned)((t - L) >> 31); // all-ones iff t < L
  return __uint_as_float((__float_as_uint(cand) & m) | (__float_as_uint(old_) & ~m));
}

// value-only max via pairwise fmax (VCC-free)
__device__ __forceinline__ float vmax48(const float* s) {
  float v1[24];
#pragma unroll
  for (int k = 0; k < 24; ++k) v1[k] = fmaxf(s[2 * k], s[2 * k + 1]);
  float v2[12];
#pragma unroll
  for (int k = 0; k < 12; ++k) v2[k] = fmaxf(v1[2 * k], v1[2 * k + 1]);
  float v3[6];
#pragma unroll
  for (int k = 0; k < 6; ++k) v3[k] = fmaxf(v2[2 * k], v2[2 * k + 1]);
  float v4[3];
#pragma unroll
  for (int k = 0; k < 3; ++k) v4[k] = fmaxf(v3[2 * k], v3[2 * k + 1]);
  return fmaxf(fmaxf(v4[0], v4[1]), v4[2]);
}

// index tree (first-index wins: move right only on strict >) — off value path
__device__ __forceinline__ int argidx48(const float* s) {
  float v1[24]; int x1[24];
#pragma unroll
  for (int k = 0; k < 24; ++k) {
    float l = s[2 * k], r = s[2 * k + 1];
    v1[k] = fmaxf(l, r);
    x1[k] = (r > l) ? 2 * k + 1 : 2 * k;
  }
  float v2[12]; int x2[12];
#pragma unroll
  for (int k = 0; k < 12; ++k) {
    float l = v1[2 * k], r = v1[2 * k + 1];
    v2[k] = fmaxf(l, r);
    x2[k] = (r > l) ? x1[2 * k + 1] : x1[2 * k];
  }
  float v3[6]; int x3[6];
#pragma unroll
  for (int k = 0; k < 6; ++k) {
    float l = v2[2 * k], r = v2[2 * k + 1];
    v3[k] = fmaxf(l, r);
    x3[k] = (r > l) ? x2[2 * k + 1] : x2[2 * k];
  }
  float v4[3]; int x4[3];
#pragma unroll
  for (int k = 0; k < 3; ++k) {
    float l = v3[2 * k], r = v3[2 * k + 1];
    v4[k] = fmaxf(l, r);
    x4[k] = (r > l) ? x3[2 * k + 1] : x3[2 * k];
  }
  float vm = fmaxf(v4[0], v4[1]);
  int xm = (v4[1] > v4[0]) ? x4[1] : x4[0];
  return (v4[2] > vm) ? x4[2] : xm;
}

__global__ __launch_bounds__(64, 1) void crf_viterbi(const float* __restrict__ logits,
                                                     const int* __restrict__ lens,
                                                     const float* __restrict__ trans,
                                                     int* __restrict__ out) {
  const int b = blockIdx.x;
  const int j = threadIdx.x;          // lanes 0..47 are live tags
  const int jj = j < DD ? j : DD - 1; // clamp for safe reads

  __shared__ unsigned char bp[ROWS * STRIDE]; // 32.5 KB backpointers (+8 pad rows)

  float tcol[DD];
#pragma unroll
  for (int i = 0; i < DD; ++i) tcol[i] = trans[i * DD + jj];

  const float* lg = logits + (size_t)b * TT * DD;
  const int L = lens[b];

  float alpha = lg[jj]; // alpha0

  // score arrays, ping-pong across steps
  float sA[DD], sB[DD];

  // V: value path of step t -> alpha updated (branchless freeze); scores to S
#define STEPV(S, T, EV)                                                  \
  {                                                                      \
    _Pragma("unroll")                                                    \
    for (int i = 0; i < DD; ++i) S[i] = readlane_f(alpha, i) + tcol[i];  \
    float best = vmax48(S);                                              \
    alpha = freeze(alpha, best + (EV), (T), L);                          \
  }
  // I: index tree of an earlier step (reads S, feeds only the bp store)
#define STEPI(S, T)                                                      \
  {                                                                      \
    int idx = argidx48(S);                                               \
    bp[(T) * STRIDE + j] = (unsigned char)idx;                           \
  }
#define RELOAD(ES, R)                                    \
  {                                                      \
    int r = (R); r = r > TT - 1 ? TT - 1 : r;            \
    ES = lg[r * DD + jj];                                \
  }

  // peel step 1 into sB (pending), ring holds rows 2..9
  float ep = lg[1 * DD + jj];
  float e0 = lg[2 * DD + jj], e1 = lg[3 * DD + jj],
        e2 = lg[4 * DD + jj], e3 = lg[5 * DD + jj],
        e4 = lg[6 * DD + jj], e5 = lg[7 * DD + jj],
        e6 = lg[8 * DD + jj], e7 = lg[9 * DD + jj];

  STEPV(sB, 1, ep);

  int tb = 2;
  for (; tb < L; tb += 8) {
    // 8 steps, ONE basic block: V(t) then I(t-1), ping-pong sA/sB
    STEPV(sA, tb + 0, e0); STEPI(sB, tb - 1); RELOAD(e0, tb + 8);
    STEPV(sB, tb + 1, e1); STEPI(sA, tb + 0); RELOAD(e1, tb + 9);
    STEPV(sA, tb + 2, e2); STEPI(sB, tb + 1); RELOAD(e2, tb + 10);
    STEPV(sB, tb + 3, e3); STEPI(sA, tb + 2); RELOAD(e3, tb + 11);
    STEPV(sA, tb + 4, e4); STEPI(sB, tb + 3); RELOAD(e4, tb + 12);
    STEPV(sB, tb + 5, e5); STEPI(sA, tb + 4); RELOAD(e5, tb + 13);
    STEPV(sA, tb + 6, e6); STEPI(sB, tb + 5); RELOAD(e6, tb + 14);
    STEPV(sB, tb + 7, e7); STEPI(sA, tb + 6); RELOAD(e7, tb + 15);
  }
  // epilogue: pending index tree is always in sB, row tb-1 (<= L+6, padded)
  STEPI(sB, tb - 1);

#undef STEPV
#undef STEPI
#undef RELOAD

  __syncthreads(); // single wave; ordering formality before backtrack

  // last_tag = argmax_j alpha (uniform on all lanes)
  float af[DD];
#pragma unroll
  for (int i = 0; i < DD; ++i) af[i] = readlane_f(alpha, i);
  int btag = argidx48(af);

  int* ob = out + (size_t)b * TT;
  if (j == 0) ob[L - 1] = btag;

  // Backtrack by function composition: H[j] = tag at time t given final tag j.
  int H = j;
  for (int tt = L - 1; tt >= 1; --tt) {
    int v = bp[tt * STRIDE + jj]; // addr independent of H -> pipelined
    H = __shfl(v, H, 64);         // H' = bp_t[H]
    if (j == btag) ob[tt - 1] = H;
  }

  // zero the padded tail t >= L
  for (int tt = L + j; tt < TT; tt += 64) ob[tt] = 0;
}

extern "C" void kernel_launch(void* const* d_in, const int* in_sizes, int n_in,
                              void* d_out, int out_size, void* d_ws, size_t ws_size,
                              hipStream_t stream) {
  const float* logits = (const float*)d_in[0];
  const int* lens     = (const int*)d_in[1];
  const float* trans  = (const float*)d_in[2];
  int* out            = (int*)d_out;
  (void)in_sizes; (void)n_in; (void)out_size; (void)d_ws; (void)ws_size;
  crf_viterbi<<<BB, 64, 0, stream>>>(logits, lens, trans, out);
}